// Round 1
// 160.028 us; speedup vs baseline: 1.1079x; 1.1079x over previous
//
#include <hip/hip_runtime.h>

#define N_NODES 50000
#define N_EDGES 600000
#define HID     128
#define NG      500
#define NB_SCAN 196   // ceil(50000/256)
#define MAXDEG  48    // ELL slots; Poisson(12) max over 50k nodes ~30; +10 sigma safe
#define ECAP    664   // compact LDS staging capacity (32 rows x mean 12 = 384; +14 sigma)
#define EBLK    586   // edge blocks (586*1024 >= 600000); grid = EBLK + 2 special blocks

typedef __attribute__((ext_vector_type(8))) short short8;   // 8 bf16 (4 VGPRs)
typedef __attribute__((ext_vector_type(4))) float f32x4;

static __device__ __forceinline__ ushort f2bf(float f) {    // RNE f32 -> bf16 bits
    uint u = __float_as_uint(f);
    return (ushort)((u + 0x7fffu + ((u >> 16) & 1u)) >> 16);
}
static __device__ __forceinline__ float bf2f(ushort h) {
    return __uint_as_float(((uint)h) << 16);
}

// ---------------- single-pass transposed-ELL fill, 4 edges/thread (+2 precompute blocks) ----

__global__ void k_ellfill(const int* __restrict__ src, const int* __restrict__ dst,
                          int* __restrict__ cnt, int* __restrict__ ell_t,
                          const float* __restrict__ W2, const float* __restrict__ W3,
                          const float* __restrict__ Wlin, const float* __restrict__ b3,
                          const float* __restrict__ blin, const int* __restrict__ batch,
                          float* __restrict__ w3buf, ushort* __restrict__ w2fh,
                          ushort* __restrict__ w2fl, int* __restrict__ starts) {
    if (blockIdx.x >= EBLK) {
        int t = threadIdx.x;
        if (blockIdx.x == EBLK) {
            // w3lin = W3 @ Wlin (128x2) + bias consts
            int k = t >> 1, j = t & 1;
            float acc = 0.f;
            for (int m = 0; m < 128; m++) acc += W3[k * 128 + m] * Wlin[m * 2 + j];
            w3buf[k * 2 + j] = acc;
            if (t < 2) {
                float c = 0.f;
                for (int m = 0; m < 128; m++) c += b3[m] * Wlin[m * 2 + t];
                w3buf[256 + t] = c + blin[t];   // const added to every non-empty graph
                w3buf[258 + t] = blin[t];       // empty-graph fallback
            }
        } else {
            // W2 -> split-bf16 (hi/lo), pre-swizzled into 16x16x32 MFMA B-fragment order:
            // elem idx = ((ntile*4 + ktile)*64 + lane)*8 + i ;
            // B[k][col] with k = ktile*32 + (lane>>4)*8 + i, col = ntile*16 + (lane&15)
            for (int idx = t; idx < 16384; idx += 256) {
                int nt = idx >> 11, kt = (idx >> 9) & 3, ln = (idx >> 3) & 63, i = idx & 7;
                int k = kt * 32 + (ln >> 4) * 8 + i;
                int col = nt * 16 + (ln & 15);
                float v = W2[k * 128 + col];
                ushort h = f2bf(v);
                w2fh[idx] = h;
                w2fl[idx] = f2bf(v - bf2f(h));
            }
            // per-graph start offsets (batch is sorted & constant): kills k_final binsearch
            for (int g = t; g <= NG; g += 256) {
                int lo = 0, hi = N_NODES;
                while (lo < hi) { int mid = (lo + hi) >> 1; if (batch[mid] < g) lo = mid + 1; else hi = mid; }
                starts[g] = lo;
            }
        }
        return;
    }
    int base = blockIdx.x * 1024 + threadIdx.x;
    #pragma unroll
    for (int u = 0; u < 4; u++) {
        int e = base + u * 256;
        if (e < N_EDGES) {
            int d = dst[e];
            int p = atomicAdd(&cnt[d], 1);
            if (p < MAXDEG) ell_t[p * N_NODES + d] = src[e];
        }
    }
}

// dinv + xd (coalesced)
__global__ void k_nodeprep(const int* __restrict__ cnt, const float* __restrict__ x,
                           float* __restrict__ dinv, float* __restrict__ xd) {
    int i = blockIdx.x * 256 + threadIdx.x;
    if (i < N_NODES) {
        float di = rsqrtf((float)cnt[i] + 1.0f);
        dinv[i] = di;
        xd[i] = x[i] * di;
    }
}

// layer-1 scalar aggregate, 4 lanes/node, plane-strided transposed reads:
// s1d[i] = {x_i*di^2 + (Σ xd[j])*di, di}
__global__ void k_s1d(const float* __restrict__ x, const float* __restrict__ xd,
                      const float* __restrict__ dinv, const int* __restrict__ cnt,
                      const int* __restrict__ ell_t, float2* __restrict__ s1d) {
    int tid = blockIdx.x * 256 + threadIdx.x;
    int i = tid >> 2, sub = tid & 3;
    if (i >= N_NODES) return;
    int c = min(cnt[i], MAXDEG);
    float acc = 0.f;
    for (int p = sub; p < c; p += 4) acc += xd[ell_t[p * N_NODES + i]];
    acc += __shfl_xor(acc, 1);
    acc += __shfl_xor(acc, 2);
    if (sub == 0) {
        float di = dinv[i];
        float2 r = {x[i] * di * di + acc * di, di};
        s1d[i] = r;
    }
}

// ---------------- Fused: reconstruct-aggregate g=A·h1, MFMA GEMM g@W2 (split-bf16),
// relu+b2, ·w3lin -> zd[N,2].  32-row tile; compact LDS staging; H tile stored as bf16
// hi/lo row-major (stride 136 -> 16B-aligned ds_read_b128 A-frags, 2-way banks = free).
// Split-bf16 product AhBh+AhBl+AlBh keeps fp32-level precision (~1e-5 rel) with MFMA rate.
// LDS total 22984 <= 23040 (45*512) -> 7 blocks/CU preserved; zpart overlays dead sjd_sh.

__global__ __launch_bounds__(256, 8) void k_gemm_fused(const float2* __restrict__ s1d,
                                                       const int* __restrict__ cnt,
                                                       const int* __restrict__ ell_t,
                                                       const float* __restrict__ W1,
                                                       const float* __restrict__ b1,
                                                       const ushort* __restrict__ w2fh,
                                                       const ushort* __restrict__ w2fl,
                                                       const float* __restrict__ b2,
                                                       const float* __restrict__ w3buf,
                                                       const float* __restrict__ dinv,
                                                       float* __restrict__ zd) {
    __shared__ __align__(16) ushort Hhi[32 * 136];   // 8704 B, [row][136] bf16-hi
    __shared__ __align__(16) ushort Hlo[32 * 136];   // 8704 B, bf16-lo
    __shared__ float2 sjd_sh[ECAP];                  // 5312 B, compacted; reused as zpart
    __shared__ int cnt_sh[32];
    __shared__ int pref_sh[33];                      // exclusive prefix; pref_sh[32] = total
    __shared__ int maxc_sh;
    int t = threadIdx.x;
    int r0 = blockIdx.x * 32;
    int lane = t & 31, grp = t >> 5;  // lane = row in tile, grp = 16-channel chunk (8 x 16)

    if (t < 32) {
        int i = r0 + t;
        int c = (i < N_NODES) ? min(cnt[i], MAXDEG) : 0;
        cnt_sh[t] = c;
        int inc = c, mx = c;
        for (int o = 1; o < 32; o <<= 1) {
            int u = __shfl_up(inc, o);
            if (t >= o) inc += u;
            mx = max(mx, __shfl_xor(mx, o));
        }
        pref_sh[t] = inc - c;
        if (t == 31) { pref_sh[32] = inc; maxc_sh = mx; }
    }
    __syncthreads();
    int total = pref_sh[32];
    int maxc  = maxc_sh;
    bool fast = (total <= ECAP);
    if (fast) {
        // staging: slot = (plane p, row ln); each 32-slot chunk reads one coalesced plane
        for (int slot = t; slot < 32 * maxc; slot += 256) {
            int p = slot >> 5, ln = slot & 31;
            if (p < cnt_sh[ln]) {
                int j = ell_t[p * N_NODES + r0 + ln];
                sjd_sh[pref_sh[ln] + p] = s1d[j];
            }
        }
    }
    __syncthreads();

    float w1r[16], b1r[16];
    #pragma unroll
    for (int kk = 0; kk < 16; kk++) { w1r[kk] = W1[grp * 16 + kk]; b1r[kk] = b1[grp * 16 + kk]; }

    float ga[16];
    #pragma unroll
    for (int kk = 0; kk < 16; kk++) ga[kk] = 0.f;
    int node = r0 + lane;
    if (node < N_NODES) {
        float2 sd = s1d[node];
        float di = sd.y, wself = sd.y * sd.y;
        #pragma unroll
        for (int kk = 0; kk < 16; kk++) ga[kk] = fmaxf(sd.x * w1r[kk] + b1r[kk], 0.f) * wself;
        int c = cnt_sh[lane];
        if (fast) {
            const float2* myrow = &sjd_sh[pref_sh[lane]];
            int p = 0;
            for (; p + 3 < c; p += 4) {
                float2 s0 = myrow[p], s1v = myrow[p+1], s2 = myrow[p+2], s3 = myrow[p+3];
                float wj0 = s0.y * di, wj1 = s1v.y * di, wj2 = s2.y * di, wj3 = s3.y * di;
                #pragma unroll
                for (int kk = 0; kk < 16; kk++) {
                    ga[kk] += fmaxf(s0.x  * w1r[kk] + b1r[kk], 0.f) * wj0
                            + fmaxf(s1v.x * w1r[kk] + b1r[kk], 0.f) * wj1
                            + fmaxf(s2.x  * w1r[kk] + b1r[kk], 0.f) * wj2
                            + fmaxf(s3.x  * w1r[kk] + b1r[kk], 0.f) * wj3;
                }
            }
            for (; p < c; p++) {
                float2 sj = myrow[p];
                float wj = sj.y * di;
                #pragma unroll
                for (int kk = 0; kk < 16; kk++)
                    ga[kk] += fmaxf(sj.x * w1r[kk] + b1r[kk], 0.f) * wj;
            }
        } else {   // overflow fallback (block-uniform, ~never taken)
            for (int p = 0; p < c; p++) {
                float2 sj = s1d[ell_t[p * N_NODES + node]];
                float wj = sj.y * di;
                #pragma unroll
                for (int kk = 0; kk < 16; kk++)
                    ga[kk] += fmaxf(sj.x * w1r[kk] + b1r[kk], 0.f) * wj;
            }
        }
    }
    // split fp32 -> bf16 hi/lo, store row-major for MFMA A-frag reads (pairs packed as u32)
    #pragma unroll
    for (int kk = 0; kk < 16; kk += 2) {
        int ch = grp * 16 + kk;
        ushort h0 = f2bf(ga[kk]);      ushort l0 = f2bf(ga[kk]     - bf2f(h0));
        ushort h1v = f2bf(ga[kk + 1]); ushort l1v = f2bf(ga[kk + 1] - bf2f(h1v));
        *(uint*)&Hhi[lane * 136 + ch] = (uint)h0 | ((uint)h1v << 16);
        *(uint*)&Hlo[lane * 136 + ch] = (uint)l0 | ((uint)l1v << 16);
    }
    __syncthreads();   // sjd_sh dead from here on

    // ---- MFMA GEMM: 32x128 = Hrow[32][128] @ W2[128][128], wave w owns cols [w*32, w*32+32)
    // mfma_f32_16x16x32_bf16: A row=lane&15, k=(lane>>4)*8+i ; B col=lane&15 ;
    // D col=lane&15, row=(lane>>4)*4+reg  (m89-verified mapping)
    int wv = t >> 6, l = t & 63;
    int l15 = l & 15, lk = l >> 4;
    f32x4 acc00 = {0.f,0.f,0.f,0.f}, acc01 = {0.f,0.f,0.f,0.f};
    f32x4 acc10 = {0.f,0.f,0.f,0.f}, acc11 = {0.f,0.f,0.f,0.f};   // [mt][nt]
    const short8* Bh = (const short8*)w2fh;
    const short8* Bl = (const short8*)w2fl;
    #pragma unroll
    for (int kt = 0; kt < 4; kt++) {
        int ao = l15 * 136 + kt * 32 + lk * 8;
        short8 ah0 = *(const short8*)&Hhi[ao];
        short8 ah1 = *(const short8*)&Hhi[ao + 16 * 136];
        short8 al0 = *(const short8*)&Hlo[ao];
        short8 al1 = *(const short8*)&Hlo[ao + 16 * 136];
        {   // nt = 0
            int ng = 2 * wv;
            short8 bh = Bh[(ng * 4 + kt) * 64 + l];
            short8 bl = Bl[(ng * 4 + kt) * 64 + l];
            acc00 = __builtin_amdgcn_mfma_f32_16x16x32_bf16(ah0, bh, acc00, 0, 0, 0);
            acc00 = __builtin_amdgcn_mfma_f32_16x16x32_bf16(ah0, bl, acc00, 0, 0, 0);
            acc00 = __builtin_amdgcn_mfma_f32_16x16x32_bf16(al0, bh, acc00, 0, 0, 0);
            acc10 = __builtin_amdgcn_mfma_f32_16x16x32_bf16(ah1, bh, acc10, 0, 0, 0);
            acc10 = __builtin_amdgcn_mfma_f32_16x16x32_bf16(ah1, bl, acc10, 0, 0, 0);
            acc10 = __builtin_amdgcn_mfma_f32_16x16x32_bf16(al1, bh, acc10, 0, 0, 0);
        }
        {   // nt = 1
            int ng = 2 * wv + 1;
            short8 bh = Bh[(ng * 4 + kt) * 64 + l];
            short8 bl = Bl[(ng * 4 + kt) * 64 + l];
            acc01 = __builtin_amdgcn_mfma_f32_16x16x32_bf16(ah0, bh, acc01, 0, 0, 0);
            acc01 = __builtin_amdgcn_mfma_f32_16x16x32_bf16(ah0, bl, acc01, 0, 0, 0);
            acc01 = __builtin_amdgcn_mfma_f32_16x16x32_bf16(al0, bh, acc01, 0, 0, 0);
            acc11 = __builtin_amdgcn_mfma_f32_16x16x32_bf16(ah1, bh, acc11, 0, 0, 0);
            acc11 = __builtin_amdgcn_mfma_f32_16x16x32_bf16(ah1, bl, acc11, 0, 0, 0);
            acc11 = __builtin_amdgcn_mfma_f32_16x16x32_bf16(al1, bh, acc11, 0, 0, 0);
        }
    }

    // epilogue: relu(+b2), project to 2 outputs, reduce 16 lanes (cols), cross-wave via LDS
    float p0[2][4], p1[2][4];
    #pragma unroll
    for (int mt = 0; mt < 2; mt++)
        #pragma unroll
        for (int r = 0; r < 4; r++) { p0[mt][r] = 0.f; p1[mt][r] = 0.f; }
    {   // nt = 0
        int colg = (2 * wv) * 16 + l15;
        float b2c = b2[colg], w0 = w3buf[colg * 2], w1c = w3buf[colg * 2 + 1];
        #pragma unroll
        for (int r = 0; r < 4; r++) {
            float v0 = fmaxf(acc00[r] + b2c, 0.f);
            float v1 = fmaxf(acc10[r] + b2c, 0.f);
            p0[0][r] += v0 * w0; p1[0][r] += v0 * w1c;
            p0[1][r] += v1 * w0; p1[1][r] += v1 * w1c;
        }
    }
    {   // nt = 1
        int colg = (2 * wv + 1) * 16 + l15;
        float b2c = b2[colg], w0 = w3buf[colg * 2], w1c = w3buf[colg * 2 + 1];
        #pragma unroll
        for (int r = 0; r < 4; r++) {
            float v0 = fmaxf(acc01[r] + b2c, 0.f);
            float v1 = fmaxf(acc11[r] + b2c, 0.f);
            p0[0][r] += v0 * w0; p1[0][r] += v0 * w1c;
            p0[1][r] += v1 * w0; p1[1][r] += v1 * w1c;
        }
    }
    #pragma unroll
    for (int o = 1; o < 16; o <<= 1) {
        #pragma unroll
        for (int mt = 0; mt < 2; mt++)
            #pragma unroll
            for (int r = 0; r < 4; r++) {
                p0[mt][r] += __shfl_xor(p0[mt][r], o);
                p1[mt][r] += __shfl_xor(p1[mt][r], o);
            }
    }
    float* zpart = (float*)sjd_sh;   // [4 waves][32 rows][2], overlays dead staging buffer
    if (l15 == 0) {
        #pragma unroll
        for (int mt = 0; mt < 2; mt++)
            #pragma unroll
            for (int r = 0; r < 4; r++) {
                int row = mt * 16 + lk * 4 + r;
                zpart[(wv * 32 + row) * 2 + 0] = p0[mt][r];
                zpart[(wv * 32 + row) * 2 + 1] = p1[mt][r];
            }
    }
    __syncthreads();
    if (t < 64) {
        int row = t >> 1, o = t & 1;
        float s = zpart[row * 2 + o] + zpart[(32 + row) * 2 + o]
                + zpart[(64 + row) * 2 + o] + zpart[(96 + row) * 2 + o];
        int rg = r0 + row;
        if (rg < N_NODES) zd[rg * 2 + o] = s * dinv[rg];
    }
}

// ---------------- Layer-3 aggregation on zd, 4 lanes/node, transposed reads -> az store ----

__global__ void k_aggz(const float* __restrict__ zd, const int* __restrict__ cnt,
                       const int* __restrict__ ell_t, const float* __restrict__ dinv,
                       float2* __restrict__ az) {
    int tid = blockIdx.x * 256 + threadIdx.x;
    int i = tid >> 2, sub = tid & 3;
    if (i >= N_NODES) return;
    const float2* Z = (const float2*)zd;
    int c = min(cnt[i], MAXDEG);
    float a0 = 0.f, a1 = 0.f;
    for (int p = sub; p < c; p += 4) {
        float2 zj = Z[ell_t[p * N_NODES + i]];
        a0 += zj.x; a1 += zj.y;
    }
    a0 += __shfl_xor(a0, 1); a1 += __shfl_xor(a1, 1);
    a0 += __shfl_xor(a0, 2); a1 += __shfl_xor(a1, 2);
    if (sub == 0) {
        float di = dinv[i];
        float2 zi = Z[i];
        float2 r = {(zi.x + a0) * di, (zi.y + a1) * di};   // zd_i*di + di*Σ zd_j
        az[i] = r;
    }
}

// ---------------- Final: one wave per graph — segment sum of az + mean + consts ----------------

__global__ __launch_bounds__(64) void k_final(const float2* __restrict__ az,
                                              const int* __restrict__ starts,
                                              const float* __restrict__ w3buf,
                                              float* __restrict__ out) {
    int g = blockIdx.x;
    int lane = threadIdx.x;
    int start = starts[g], end = starts[g + 1];
    float a0 = 0.f, a1 = 0.f;
    for (int n = start + lane; n < end; n += 64) {
        float2 v = az[n];
        a0 += v.x; a1 += v.y;
    }
    for (int o = 32; o; o >>= 1) { a0 += __shfl_xor(a0, o); a1 += __shfl_xor(a1, o); }
    if (lane == 0) {
        if (end > start) {
            float inv = 1.0f / (float)(end - start);
            out[g * 2 + 0] = a0 * inv + w3buf[256];
            out[g * 2 + 1] = a1 * inv + w3buf[257];
        } else {
            out[g * 2 + 0] = w3buf[258];
            out[g * 2 + 1] = w3buf[259];
        }
    }
}

// ---------------- launch ----------------

extern "C" void kernel_launch(void* const* d_in, const int* in_sizes, int n_in,
                              void* d_out, int out_size, void* d_ws, size_t ws_size,
                              hipStream_t stream) {
    const float* x    = (const float*)d_in[0];
    const float* W1   = (const float*)d_in[1];
    const float* b1   = (const float*)d_in[2];
    const float* W2   = (const float*)d_in[3];
    const float* b2   = (const float*)d_in[4];
    const float* W3   = (const float*)d_in[5];
    const float* b3   = (const float*)d_in[6];
    const float* Wlin = (const float*)d_in[7];
    const float* blin = (const float*)d_in[8];
    const int*   eidx = (const int*)d_in[9];
    const int*   batch= (const int*)d_in[10];
    const int* esrc = eidx;
    const int* edst = eidx + N_EDGES;
    float* out = (float*)d_out;

    char* w = (char*)d_ws;
    size_t off = 0;
    auto alloc = [&](size_t bytes) { size_t o = off; off = (off + bytes + 255) & ~(size_t)255; return o; };
    int*   cnt    = (int*)  (w + alloc(N_NODES * 4));
    int*   ell_t  = (int*)  (w + alloc((size_t)N_NODES * MAXDEG * 4));   // 9.6 MB, plane-major
    float* dinv   = (float*)(w + alloc(N_NODES * 4));
    float* xd     = (float*)(w + alloc(N_NODES * 4));
    float2* s1d   = (float2*)(w + alloc((size_t)N_NODES * 8));
    float* w3buf  = (float*)(w + alloc(260 * 4));
    float* zd     = (float*)(w + alloc((size_t)N_NODES * 2 * 4));
    float2* az    = (float2*)(w + alloc((size_t)N_NODES * 8));
    ushort* w2fh  = (ushort*)(w + alloc(16384 * 2));   // W2 bf16-hi, MFMA B-frag order
    ushort* w2fl  = (ushort*)(w + alloc(16384 * 2));   // W2 bf16-lo
    int*   starts = (int*)  (w + alloc((NG + 4) * 4)); // per-graph node range starts

    const int QB = (N_NODES * 4 + 255) / 256;   // 782 (4 lanes/node)
    // 1: zero cnt
    hipMemsetAsync(cnt, 0, N_NODES * 4, stream);
    // 2: transposed-ELL build (4 edges/thread) + w3lin / W2-frag / starts precompute
    k_ellfill<<<EBLK + 2, 256, 0, stream>>>(esrc, edst, cnt, ell_t, W2, W3, Wlin, b3, blin,
                                            batch, w3buf, w2fh, w2fl, starts);
    // 3: dinv + xd
    k_nodeprep<<<NB_SCAN, 256, 0, stream>>>(cnt, x, dinv, xd);
    // 4: layer-1 scalar aggregate (4 lanes/node, plane-strided)
    k_s1d<<<QB, 256, 0, stream>>>(x, xd, dinv, cnt, ell_t, s1d);
    // 5: fused reconstruct + MFMA GEMM + relu + projection -> zd [N,2]
    k_gemm_fused<<<(N_NODES + 31) / 32, 256, 0, stream>>>(s1d, cnt, ell_t,
                                                          W1, b1, w2fh, w2fl, b2, w3buf,
                                                          dinv, zd);
    // 6: layer-3 aggregation on zd (4 lanes/node, plane-strided) -> az
    k_aggz<<<QB, 256, 0, stream>>>(zd, cnt, ell_t, dinv, az);
    // 7: per-graph segment mean + consts (one wave per graph, precomputed starts)
    k_final<<<NG, 64, 0, stream>>>(az, starts, w3buf, out);
}